// Round 13
// baseline (1130.383 us; speedup 1.0000x reference)
//
#include <hip/hip_runtime.h>
#include <stdint.h>

typedef unsigned short u16;
typedef __attribute__((ext_vector_type(8))) short bf16x8_t;
typedef __attribute__((ext_vector_type(4))) float f32x4_t;

__device__ __forceinline__ float bl(u16 x) {
  union { unsigned u; float f; } c; c.u = ((unsigned)x) << 16; return c.f;
}
__device__ __forceinline__ u16 fb(float x) {
  union { float f; unsigned u; } c; c.f = x;
  unsigned r = c.u + 0x7fffu + ((c.u >> 16) & 1u);
  return (u16)(r >> 16);
}

__global__ void sentinel_kernel(float* out, int n) {
  int i = blockIdx.x * 256 + threadIdx.x;
  if (i < n) out[i] = 12345.f;
}

// ---------------- weight transpose: wT[n][k] = fb(W[k][n]) ----------------
struct TSeg { const float* src; u16* dst; };
struct TArgs { TSeg s[23]; };
__global__ void transpose_w(TArgs a) {
  __shared__ u16 sT[128][132];
  const float* src = a.s[blockIdx.x].src;
  u16* dst = a.s[blockIdx.x].dst;
  for (int e = threadIdx.x; e < 16384; e += 256) {
    int k = e >> 7, n = e & 127;
    sT[n][k] = fb(src[e]);
  }
  __syncthreads();
  for (int e = threadIdx.x; e < 16384; e += 256) {
    int n = e >> 7, k = e & 127;
    dst[e] = sT[n][k];
  }
}

// decoder W1 (128x64) -> bf16 W1^T [64][128]
__global__ void transpose_w1d(const float* __restrict__ src, u16* __restrict__ dst) {
  __shared__ u16 sT[64][132];
  for (int e = threadIdx.x; e < 8192; e += 256) {
    int k = e >> 6, n = e & 63;
    sT[n][k] = fb(src[e]);
  }
  __syncthreads();
  for (int e = threadIdx.x; e < 8192; e += 256) {
    int n = e >> 7, k = e & 127;
    dst[e] = sT[n][k];
  }
}

// ---------------- CSR build + receiver-sort ----------------
__global__ void deg_count(const int* __restrict__ ei, int* __restrict__ cnt, int E) {
  int e = blockIdx.x * 256 + threadIdx.x;
  if (e < E) atomicAdd(&cnt[ei[E + e]], 1);
}
__global__ void scan1(const int* __restrict__ cnt, int* __restrict__ part,
                      int* __restrict__ bsum, int N) {
  __shared__ int s[256];
  int i = blockIdx.x * 256 + threadIdx.x;
  s[threadIdx.x] = (i < N) ? cnt[i] : 0;
  __syncthreads();
#pragma unroll
  for (int o = 1; o < 256; o <<= 1) {
    int t = (threadIdx.x >= o) ? s[threadIdx.x - o] : 0;
    __syncthreads();
    s[threadIdx.x] += t;
    __syncthreads();
  }
  if (i < N) part[i] = s[threadIdx.x];
  if (threadIdx.x == 255) bsum[blockIdx.x] = s[255];
}
__global__ void scan2(int* bsum, int nb) {
  __shared__ int s[256];
  __shared__ int carry;
  if (threadIdx.x == 0) carry = 0;
  __syncthreads();
  for (int base = 0; base < nb; base += 256) {
    int i = base + threadIdx.x;
    int v = (i < nb) ? bsum[i] : 0;
    s[threadIdx.x] = v;
    __syncthreads();
#pragma unroll
    for (int o = 1; o < 256; o <<= 1) {
      int t = (threadIdx.x >= o) ? s[threadIdx.x - o] : 0;
      __syncthreads();
      s[threadIdx.x] += t;
      __syncthreads();
    }
    int exc = s[threadIdx.x] - v + carry;
    if (i < nb) bsum[i] = exc;
    __syncthreads();
    if (threadIdx.x == 255) carry += s[255];
    __syncthreads();
  }
}
__global__ void scan3(const int* __restrict__ part, const int* __restrict__ bsum,
                      int* __restrict__ start, int N) {
  int i = blockIdx.x * 256 + threadIdx.x;
  if (i < N) start[i + 1] = part[i] + bsum[i >> 8];
  if (i == 0) start[0] = 0;
}
__global__ void fill_slot(const int* __restrict__ ei, int* __restrict__ cnt2,
                          const int* __restrict__ start, int* __restrict__ sortedS,
                          int* __restrict__ sortedR, int E) {
  int e = blockIdx.x * 256 + threadIdx.x;
  if (e >= E) return;
  int s = ei[e], r = ei[E + e];
  int p = atomicAdd(&cnt2[r], 1);
  int slot = start[r] + p;
  sortedS[slot] = s;
  sortedR[slot] = r;
}

// ---------------- fused encoder (node path only now) ----------------
template <int K, bool DUAL, bool NODE>
__global__ __launch_bounds__(256, 2) void encode_fused(
    const float* __restrict__ fa, const float* __restrict__ fb_, const float* __restrict__ fc,
    const float* __restrict__ fd, const float* __restrict__ fe,
    const float* __restrict__ fmean, const float* __restrict__ fstd,
    const int* __restrict__ sArr, const int* __restrict__ rArr,
    const float* __restrict__ w1f, const float* __restrict__ b1f,
    const u16* __restrict__ wt2, const float* __restrict__ b2, const float* __restrict__ gg,
    const float* __restrict__ bb, u16* __restrict__ out,
    const u16* __restrict__ wtA2, const u16* __restrict__ wtB2, u16* __restrict__ xhA,
    u16* __restrict__ xhB, float* __restrict__ aggr, int M) {
  __shared__ float sW1[K * 128];
  __shared__ float sB1[128];
  __shared__ float sM[16], sS[16];
  __shared__ u16 sH[64][136];
  __shared__ u16 sO1[DUAL ? 64 : 1][136];
  const int tid = threadIdx.x;
  const int wave = tid >> 6, lane = tid & 63;
  const int q = lane >> 4, l16 = lane & 15;
  const int m0 = blockIdx.x * 64;
  const int rowb = wave * 16 + q * 4;
  const int arow = m0 + wave * 16 + l16;
  const int arc = arow < M ? arow : M - 1;

  float rv[4], rq[5];
  int s_, r_;
  if constexpr (NODE) {
    rv[0] = fa[arc]; rv[1] = fb_[arc]; rv[2] = fc[arc]; rv[3] = fd[arc];
#pragma unroll
    for (int j = 0; j < 5; ++j) rq[j] = fe[(size_t)arc * 5 + j];
  } else {
    s_ = sArr[arc]; r_ = rArr[arc];
    rv[0] = fa[s_ * 2] - fa[r_ * 2];
    rv[1] = fa[s_ * 2 + 1] - fa[r_ * 2 + 1];
    rv[2] = fb_[s_];
    rv[3] = fb_[r_];
  }

  for (int i = tid; i < K * 128; i += 256) sW1[i] = w1f[i];
  if (tid < 128) sB1[tid] = b1f[tid];
  if (tid < K) { sM[tid] = fmean[tid]; sS[tid] = fstd[tid]; }
  __syncthreads();

  float fr[K];
  if constexpr (NODE) {
    float x[9];
    x[0] = rv[0]; x[1] = rv[0] - rv[1];
    x[2] = rv[2]; x[3] = rv[2] - rv[3];
#pragma unroll
    for (int j = 0; j < 5; ++j) x[4 + j] = rq[j];
#pragma unroll
    for (int k = 0; k < 9; ++k) fr[k] = (x[k] - sM[k]) / sS[k];
  } else {
    float d = sqrtf(rv[0] * rv[0] + rv[1] * rv[1]);
    float x[4] = {rv[0], rv[1], d, rv[2] - rv[3]};
#pragma unroll
    for (int k = 0; k < 4; ++k) fr[k] = (x[k] - sM[k]) / sS[k];
  }

  f32x4_t acc[8];
#pragma unroll
  for (int b = 0; b < 8; ++b) acc[b] = (f32x4_t){0.f, 0.f, 0.f, 0.f};
#pragma unroll
  for (int kk = 0; kk < 4; ++kk) {
    union { u16 u[8]; bf16x8_t v; } cv;
#pragma unroll
    for (int j = 0; j < 8; ++j) {
      int col = kk * 32 + q * 8 + j;
      float h = sB1[col];
#pragma unroll
      for (int k = 0; k < K; ++k) h += fr[k] * sW1[k * 128 + col];
      cv.u[j] = fb(h > 0.f ? h : 0.f);
    }
#pragma unroll
    for (int nt = 0; nt < 8; ++nt) {
      bf16x8_t bfv = *(const bf16x8_t*)(wt2 + (size_t)(nt * 16 + l16) * 128 + kk * 32 + q * 8);
      acc[nt] = __builtin_amdgcn_mfma_f32_16x16x32_bf16(cv.v, bfv, acc[nt], 0, 0, 0);
    }
  }

  float bcol[8], gcol[8], becol[8];
#pragma unroll
  for (int nt = 0; nt < 8; ++nt) {
    bcol[nt] = b2[nt * 16 + l16];
    gcol[nt] = gg[nt * 16 + l16];
    becol[nt] = bb[nt * 16 + l16];
  }
  float s[4] = {0, 0, 0, 0}, ss[4] = {0, 0, 0, 0};
#pragma unroll
  for (int r = 0; r < 4; ++r)
#pragma unroll
    for (int nt = 0; nt < 8; ++nt) {
      float v = acc[nt][r] + bcol[nt];
      s[r] += v;
      ss[r] += v * v;
    }
#pragma unroll
  for (int r = 0; r < 4; ++r) {
#pragma unroll
    for (int m = 1; m <= 8; m <<= 1) {
      s[r] += __shfl_xor(s[r], m, 64);
      ss[r] += __shfl_xor(ss[r], m, 64);
    }
  }
#pragma unroll
  for (int r = 0; r < 4; ++r) {
    float mean = s[r] * (1.f / 128.f);
    float var = fmaxf(ss[r] * (1.f / 128.f) - mean * mean, 0.f);
    float rstd = rsqrtf(var + 1e-5f);
#pragma unroll
    for (int nt = 0; nt < 8; ++nt) {
      float v = (acc[nt][r] + bcol[nt] - mean) * rstd * gcol[nt] + becol[nt];
      sH[rowb + r][nt * 16 + l16] = fb(v);
    }
  }
  __syncthreads();
#pragma unroll
  for (int it = 0; it < 4; ++it) {
    int lin = it * 256 + tid;
    int row = lin >> 4, ch = (lin & 15) * 8;
    int grow = m0 + row;
    if (grow >= M) continue;
    *(uint4*)(out + (size_t)grow * 128 + ch) = *(uint4*)(&sH[row][ch]);
  }

  if constexpr (DUAL) {
    {
      float4 z = make_float4(0.f, 0.f, 0.f, 0.f);
#pragma unroll
      for (int it = 0; it < 8; ++it) {
        int lin = it * 256 + tid;
        int row = lin >> 5, c4 = (lin & 31) * 4;
        int grow = m0 + row;
        if (grow < M) *(float4*)(aggr + (size_t)grow * 128 + c4) = z;
      }
    }
    f32x4_t a0[8], a1[8];
#pragma unroll
    for (int b = 0; b < 8; ++b) {
      a0[b] = (f32x4_t){0.f, 0.f, 0.f, 0.f};
      a1[b] = (f32x4_t){0.f, 0.f, 0.f, 0.f};
    }
#pragma unroll
    for (int kk = 0; kk < 4; ++kk) {
      bf16x8_t af = *(const bf16x8_t*)(&sH[wave * 16 + l16][kk * 32 + q * 8]);
#pragma unroll
      for (int nt = 0; nt < 8; ++nt) {
        bf16x8_t b0 = *(const bf16x8_t*)(wtA2 + (size_t)(nt * 16 + l16) * 128 + kk * 32 + q * 8);
        bf16x8_t b1v = *(const bf16x8_t*)(wtB2 + (size_t)(nt * 16 + l16) * 128 + kk * 32 + q * 8);
        a0[nt] = __builtin_amdgcn_mfma_f32_16x16x32_bf16(af, b0, a0[nt], 0, 0, 0);
        a1[nt] = __builtin_amdgcn_mfma_f32_16x16x32_bf16(af, b1v, a1[nt], 0, 0, 0);
      }
    }
    __syncthreads();
#pragma unroll
    for (int r = 0; r < 4; ++r)
#pragma unroll
      for (int nt = 0; nt < 8; ++nt) {
        sH[rowb + r][nt * 16 + l16] = fb(a0[nt][r]);
        sO1[rowb + r][nt * 16 + l16] = fb(a1[nt][r]);
      }
    __syncthreads();
#pragma unroll
    for (int it = 0; it < 4; ++it) {
      int lin = it * 256 + tid;
      int row = lin >> 4, ch = (lin & 15) * 8;
      int grow = m0 + row;
      if (grow >= M) continue;
      *(uint4*)(xhA + (size_t)grow * 128 + ch) = *(uint4*)(&sH[row][ch]);
      *(uint4*)(xhB + (size_t)grow * 128 + ch) = *(uint4*)(&sO1[row][ch]);
    }
  }
}

// ---------------- fused node-update (+ next-step dual GEMM / + fused decoder) --------
template <bool DEC>
__global__ __launch_bounds__(256, 2) void node_fused_2w(
    u16* __restrict__ xh, float* __restrict__ aggr, const u16* __restrict__ wtA,
    const u16* __restrict__ wtB, const float* __restrict__ b1, const u16* __restrict__ wt2,
    const float* __restrict__ b2, const float* __restrict__ gg, const float* __restrict__ bb,
    const u16* __restrict__ wtA2, const u16* __restrict__ wtB2, u16* __restrict__ xhA,
    u16* __restrict__ xhB,
    const u16* __restrict__ w1t, const float* __restrict__ db1,
    const float* __restrict__ w2d, const float* __restrict__ db2, float* __restrict__ outp,
    int M) {
  __shared__ u16 sH[64][136];
  __shared__ u16 sO1[DEC ? 1 : 64][136];
  __shared__ float sW2d[DEC ? 320 : 1];
  __shared__ float sDb1[DEC ? 64 : 1];
  const int tid = threadIdx.x;
  const int wave = tid >> 6, lane = tid & 63;
  const int q = lane >> 4, l16 = lane & 15;
  const int m0 = blockIdx.x * 64;
  const int rowb = wave * 16 + q * 4;
  const int arow = m0 + wave * 16 + l16;
  const int arc = arow < M ? arow : M - 1;

  if constexpr (DEC) {
    for (int i = tid; i < 320; i += 256) sW2d[i] = w2d[i];
    if (tid < 64) sDb1[tid] = db1[tid];
  }

  bf16x8_t xf[4], af_[4];
#pragma unroll
  for (int kk = 0; kk < 4; ++kk) {
    xf[kk] = *(const bf16x8_t*)(xh + (size_t)arc * 128 + kk * 32 + q * 8);
    const float* ap = aggr + (size_t)arc * 128 + kk * 32 + q * 8;
    union { u16 u[8]; bf16x8_t v; } cv;
#pragma unroll
    for (int j = 0; j < 8; ++j) cv.u[j] = fb(ap[j]);
    af_[kk] = cv.v;
  }

  f32x4_t acc[8];
#pragma unroll
  for (int b = 0; b < 8; ++b) acc[b] = (f32x4_t){0.f, 0.f, 0.f, 0.f};
#pragma unroll
  for (int kk = 0; kk < 4; ++kk) {
#pragma unroll
    for (int nt = 0; nt < 8; ++nt) {
      bf16x8_t bA = *(const bf16x8_t*)(wtA + (size_t)(nt * 16 + l16) * 128 + kk * 32 + q * 8);
      bf16x8_t bB = *(const bf16x8_t*)(wtB + (size_t)(nt * 16 + l16) * 128 + kk * 32 + q * 8);
      acc[nt] = __builtin_amdgcn_mfma_f32_16x16x32_bf16(af_[kk], bA, acc[nt], 0, 0, 0);
      acc[nt] = __builtin_amdgcn_mfma_f32_16x16x32_bf16(xf[kk], bB, acc[nt], 0, 0, 0);
    }
  }
  float bcol1[8];
#pragma unroll
  for (int nt = 0; nt < 8; ++nt) bcol1[nt] = b1[nt * 16 + l16];
#pragma unroll
  for (int r = 0; r < 4; ++r)
#pragma unroll
    for (int nt = 0; nt < 8; ++nt) {
      float v = acc[nt][r] + bcol1[nt];
      sH[rowb + r][nt * 16 + l16] = fb(v > 0.f ? v : 0.f);
    }
  __syncthreads();

  f32x4_t acc2[8];
#pragma unroll
  for (int b = 0; b < 8; ++b) acc2[b] = (f32x4_t){0.f, 0.f, 0.f, 0.f};
#pragma unroll
  for (int kk = 0; kk < 4; ++kk) {
    bf16x8_t afm = *(const bf16x8_t*)(&sH[wave * 16 + l16][kk * 32 + q * 8]);
#pragma unroll
    for (int nt = 0; nt < 8; ++nt) {
      bf16x8_t bfv = *(const bf16x8_t*)(wt2 + (size_t)(nt * 16 + l16) * 128 + kk * 32 + q * 8);
      acc2[nt] = __builtin_amdgcn_mfma_f32_16x16x32_bf16(afm, bfv, acc2[nt], 0, 0, 0);
    }
  }
  float bcol[8], gcol[8], becol[8];
#pragma unroll
  for (int nt = 0; nt < 8; ++nt) {
    bcol[nt] = b2[nt * 16 + l16];
    gcol[nt] = gg[nt * 16 + l16];
    becol[nt] = bb[nt * 16 + l16];
  }
  float s[4] = {0, 0, 0, 0}, ss[4] = {0, 0, 0, 0};
#pragma unroll
  for (int r = 0; r < 4; ++r)
#pragma unroll
    for (int nt = 0; nt < 8; ++nt) {
      float v = acc2[nt][r] + bcol[nt];
      s[r] += v;
      ss[r] += v * v;
    }
#pragma unroll
  for (int r = 0; r < 4; ++r) {
#pragma unroll
    for (int m = 1; m <= 8; m <<= 1) {
      s[r] += __shfl_xor(s[r], m, 64);
      ss[r] += __shfl_xor(ss[r], m, 64);
    }
  }
  __syncthreads();
#pragma unroll
  for (int r = 0; r < 4; ++r) {
    float mean = s[r] * (1.f / 128.f);
    float var = fmaxf(ss[r] * (1.f / 128.f) - mean * mean, 0.f);
    float rstd = rsqrtf(var + 1e-5f);
#pragma unroll
    for (int nt = 0; nt < 8; ++nt) {
      float v = (acc2[nt][r] + bcol[nt] - mean) * rstd * gcol[nt] + becol[nt];
      sH[rowb + r][nt * 16 + l16] = fb(v);
    }
  }
  __syncthreads();

  bf16x8_t nf[4];
#pragma unroll
  for (int kk = 0; kk < 4; ++kk) {
    u16 y8[8];
    *(uint4*)y8 = *(uint4*)(&sH[wave * 16 + l16][kk * 32 + q * 8]);
#pragma unroll
    for (int j = 0; j < 8; ++j) y8[j] = fb(bl(y8[j]) + bl((u16)xf[kk][j]));
    nf[kk] = *(bf16x8_t*)y8;
    if constexpr (!DEC) {
      if (arow < M)
        *(uint4*)(xh + (size_t)arow * 128 + kk * 32 + q * 8) = *(uint4*)y8;
    }
  }

  if constexpr (DEC) {
    __syncthreads();
    float* sHf = (float*)&sH[0][0];
    f32x4_t dacc[4];
#pragma unroll
    for (int b = 0; b < 4; ++b) dacc[b] = (f32x4_t){0.f, 0.f, 0.f, 0.f};
#pragma unroll
    for (int kk = 0; kk < 4; ++kk) {
#pragma unroll
      for (int nt = 0; nt < 4; ++nt) {
        bf16x8_t bfv = *(const bf16x8_t*)(w1t + (size_t)(nt * 16 + l16) * 128 + kk * 32 + q * 8);
        dacc[nt] = __builtin_amdgcn_mfma_f32_16x16x32_bf16(nf[kk], bfv, dacc[nt], 0, 0, 0);
      }
    }
#pragma unroll
    for (int r = 0; r < 4; ++r)
#pragma unroll
      for (int nt = 0; nt < 4; ++nt) {
        float h = dacc[nt][r] + sDb1[nt * 16 + l16];
        float hs = h * (1.f / (1.f + __expf(-h)));
        sHf[(rowb + r) * 68 + nt * 16 + l16] = hs;
      }
    __syncthreads();
    int row = tid >> 2, tq = tid & 3;
    int grow = m0 + row;
    if (grow < M) {
#pragma unroll
      for (int t0 = 0; t0 < 2; ++t0) {
        int t = (t0 == 0) ? tq : (tq == 0 ? 4 : -1);
        if (t < 0) continue;
        float p = db2[t];
        for (int k = 0; k < 64; ++k) p += sHf[row * 68 + k] * sW2d[k * 5 + t];
        outp[(size_t)grow * 5 + t] = (float)(t + 1) * p;
      }
    }
    return;
  }

  if (wtA2 == nullptr) return;

  if (arow < M) {
    float4 z = make_float4(0.f, 0.f, 0.f, 0.f);
#pragma unroll
    for (int kk = 0; kk < 4; ++kk) {
      *(float4*)(aggr + (size_t)arow * 128 + kk * 32 + q * 8) = z;
      *(float4*)(aggr + (size_t)arow * 128 + kk * 32 + q * 8 + 4) = z;
    }
  }

  f32x4_t a0[8], a1[8];
#pragma unroll
  for (int b = 0; b < 8; ++b) {
    a0[b] = (f32x4_t){0.f, 0.f, 0.f, 0.f};
    a1[b] = (f32x4_t){0.f, 0.f, 0.f, 0.f};
  }
#pragma unroll
  for (int kk = 0; kk < 4; ++kk) {
#pragma unroll
    for (int nt = 0; nt < 8; ++nt) {
      bf16x8_t b0 = *(const bf16x8_t*)(wtA2 + (size_t)(nt * 16 + l16) * 128 + kk * 32 + q * 8);
      bf16x8_t b1v = *(const bf16x8_t*)(wtB2 + (size_t)(nt * 16 + l16) * 128 + kk * 32 + q * 8);
      a0[nt] = __builtin_amdgcn_mfma_f32_16x16x32_bf16(nf[kk], b0, a0[nt], 0, 0, 0);
      a1[nt] = __builtin_amdgcn_mfma_f32_16x16x32_bf16(nf[kk], b1v, a1[nt], 0, 0, 0);
    }
  }
  __syncthreads();
#pragma unroll
  for (int r = 0; r < 4; ++r)
#pragma unroll
    for (int nt = 0; nt < 8; ++nt) {
      sH[rowb + r][nt * 16 + l16] = fb(a0[nt][r]);
      sO1[rowb + r][nt * 16 + l16] = fb(a1[nt][r]);
    }
  __syncthreads();
#pragma unroll
  for (int it = 0; it < 4; ++it) {
    int lin = it * 256 + tid;
    int row = lin >> 4, ch = (lin & 15) * 8;
    int grow = m0 + row;
    if (grow >= M) continue;
    *(uint4*)(xhA + (size_t)grow * 128 + ch) = *(uint4*)(&sH[row][ch]);
    *(uint4*)(xhB + (size_t)grow * 128 + ch) = *(uint4*)(&sO1[row][ch]);
  }
}

// ---------------- fused edge kernel ----------------
// ENC=true (step 0): edge encoder fused in -- features gathered inline, GEMM1 via
// LDS-staged W1, MFMA vs wee2T, LN -> sHm, store ehP (steps 1-2 read it), read
// ehf A-fragments back from LDS. Champion body below is UNCHANGED.
template <bool CSR, bool LAST, bool ENC>
__global__ __launch_bounds__(256, 2) void edge_fused(
    u16* __restrict__ eh, const u16* __restrict__ xhA, const u16* __restrict__ xhB,
    const u16* __restrict__ wtC, const float* __restrict__ b1, const u16* __restrict__ wt2,
    const float* __restrict__ b2, const float* __restrict__ gg, const float* __restrict__ bb,
    const int* __restrict__ sArr, const int* __restrict__ rArr,
    const int* __restrict__ startp, float* __restrict__ aggr,
    const float* __restrict__ ew1, const float* __restrict__ eb1,
    const u16* __restrict__ ewt2, const float* __restrict__ eb2,
    const float* __restrict__ eg, const float* __restrict__ ebe,
    const float* __restrict__ emean, const float* __restrict__ estd,
    const float* __restrict__ mp, const float* __restrict__ tarr, int E) {
  __shared__ u16 sHm[64][136];
  __shared__ u16 sHe[LAST ? 1 : 64][136];
  __shared__ int sR[64];
  __shared__ float sB1[128];
  __shared__ float sW1e[ENC ? 512 : 1];
  __shared__ float sB1e[ENC ? 128 : 1];
  __shared__ float sMS[ENC ? 8 : 1];
  const int tid = threadIdx.x;
  const int wave = tid >> 6, lane = tid & 63;
  const int q = lane >> 4, l16 = lane & 15;
  const int m0 = blockIdx.x * 64;
  const int rowb = wave * 16 + q * 4;
  int arow = m0 + wave * 16 + l16;
  int arc = arow < E ? arow : E - 1;

  if (tid < 64) {
    int e = m0 + tid;
    sR[tid] = (e < E) ? rArr[e] : -1;
  }
  if (tid < 128) sB1[tid] = b1[tid];

  int psv[4], prv[4];
#pragma unroll
  for (int it = 0; it < 4; ++it) {
    int lin = it * 256 + tid;
    int ge = m0 + (lin >> 4);
    int gc = ge < E ? ge : E - 1;
    psv[it] = sArr[gc];
    prv[it] = rArr[gc];
  }

  bf16x8_t ehf[4];
  if constexpr (ENC) {
    // ---- inline edge encoder ----
    for (int i = tid; i < 512; i += 256) sW1e[i] = ew1[i];
    if (tid < 128) sB1e[tid] = eb1[tid];
    if (tid < 4) { sMS[tid] = emean[tid]; sMS[4 + tid] = estd[tid]; }
    int es = sArr[arc], er = rArr[arc];
    float r0 = mp[es * 2] - mp[er * 2];
    float r1 = mp[es * 2 + 1] - mp[er * 2 + 1];
    float r2 = tarr[es], r3 = tarr[er];
    __syncthreads();
    float dd = sqrtf(r0 * r0 + r1 * r1);
    float fx[4] = {r0, r1, dd, r2 - r3};
    float fr[4];
#pragma unroll
    for (int k = 0; k < 4; ++k) fr[k] = (fx[k] - sMS[k]) / sMS[4 + k];

    f32x4_t eacc[8];
#pragma unroll
    for (int b = 0; b < 8; ++b) eacc[b] = (f32x4_t){0.f, 0.f, 0.f, 0.f};
#pragma unroll
    for (int kk = 0; kk < 4; ++kk) {
      union { u16 u[8]; bf16x8_t v; } cv;
#pragma unroll
      for (int j = 0; j < 8; ++j) {
        int col = kk * 32 + q * 8 + j;
        float h = sB1e[col];
#pragma unroll
        for (int k = 0; k < 4; ++k) h += fr[k] * sW1e[k * 128 + col];
        cv.u[j] = fb(h > 0.f ? h : 0.f);
      }
#pragma unroll
      for (int nt = 0; nt < 8; ++nt) {
        bf16x8_t bfv =
            *(const bf16x8_t*)(ewt2 + (size_t)(nt * 16 + l16) * 128 + kk * 32 + q * 8);
        eacc[nt] = __builtin_amdgcn_mfma_f32_16x16x32_bf16(cv.v, bfv, eacc[nt], 0, 0, 0);
      }
    }
    float s0[4] = {0, 0, 0, 0}, ss0[4] = {0, 0, 0, 0};
    float eb2c[8];
#pragma unroll
    for (int nt = 0; nt < 8; ++nt) eb2c[nt] = eb2[nt * 16 + l16];
#pragma unroll
    for (int r = 0; r < 4; ++r)
#pragma unroll
      for (int nt = 0; nt < 8; ++nt) {
        float v = eacc[nt][r] + eb2c[nt];
        s0[r] += v;
        ss0[r] += v * v;
      }
#pragma unroll
    for (int r = 0; r < 4; ++r) {
#pragma unroll
      for (int m = 1; m <= 8; m <<= 1) {
        s0[r] += __shfl_xor(s0[r], m, 64);
        ss0[r] += __shfl_xor(ss0[r], m, 64);
      }
    }
#pragma unroll
    for (int r = 0; r < 4; ++r) {
      float mean = s0[r] * (1.f / 128.f);
      float var = fmaxf(ss0[r] * (1.f / 128.f) - mean * mean, 0.f);
      float rstd = rsqrtf(var + 1e-5f);
#pragma unroll
      for (int nt = 0; nt < 8; ++nt) {
        int col = nt * 16 + l16;
        float v = (eacc[nt][r] + eb2c[nt] - mean) * rstd * eg[col] + ebe[col];
        sHm[rowb + r][col] = fb(v);
      }
    }
    __syncthreads();
    // store ehP (steps 1-2 read it) + read A-fragments from LDS
#pragma unroll
    for (int it = 0; it < 4; ++it) {
      int lin = it * 256 + tid;
      int row = lin >> 4, ch = (lin & 15) * 8;
      int grow = m0 + row;
      if (grow >= E) continue;
      *(uint4*)(eh + (size_t)grow * 128 + ch) = *(uint4*)(&sHm[row][ch]);
    }
#pragma unroll
    for (int kk = 0; kk < 4; ++kk)
      ehf[kk] = *(const bf16x8_t*)(&sHm[wave * 16 + l16][kk * 32 + q * 8]);
    __syncthreads();  // all reads of encode-sHm done before accC overwrite
  } else {
#pragma unroll
    for (int kk = 0; kk < 4; ++kk)
      ehf[kk] = *(const bf16x8_t*)(eh + (size_t)arc * 128 + kk * 32 + q * 8);
  }

  f32x4_t accC[8];
#pragma unroll
  for (int b = 0; b < 8; ++b) accC[b] = (f32x4_t){0.f, 0.f, 0.f, 0.f};
#pragma unroll
  for (int kk = 0; kk < 4; ++kk) {
#pragma unroll
    for (int nt = 0; nt < 8; ++nt) {
      bf16x8_t bfv = *(const bf16x8_t*)(wtC + (size_t)(nt * 16 + l16) * 128 + kk * 32 + q * 8);
      accC[nt] = __builtin_amdgcn_mfma_f32_16x16x32_bf16(ehf[kk], bfv, accC[nt], 0, 0, 0);
    }
  }
  __builtin_amdgcn_sched_barrier(0);

  uint4 pAr[4], pBs[4], pAs[4], pBr[4];
#pragma unroll
  for (int it = 0; it < 4; ++it) {
    int ch = ((it * 256 + tid) & 15) * 8;
    pAr[it] = *(const uint4*)(xhA + (size_t)prv[it] * 128 + ch);
    pBs[it] = *(const uint4*)(xhB + (size_t)psv[it] * 128 + ch);
    if constexpr (!LAST) {
      pAs[it] = *(const uint4*)(xhA + (size_t)psv[it] * 128 + ch);
      pBr[it] = *(const uint4*)(xhB + (size_t)prv[it] * 128 + ch);
    }
  }

#pragma unroll
  for (int r = 0; r < 4; ++r)
#pragma unroll
    for (int nt = 0; nt < 8; ++nt) sHm[rowb + r][nt * 16 + l16] = fb(accC[nt][r]);
  __syncthreads();

#pragma unroll
  for (int it = 0; it < 4; ++it) {
    int lin = it * 256 + tid;
    int row = lin >> 4, ch = (lin & 15) * 8;
    bool ok = (m0 + row) < E;
    u16 t8[8], ar[8], as_[8], br[8], bs[8], hm[8], he[8];
    *(uint4*)t8 = *(uint4*)(&sHm[row][ch]);
    *(uint4*)ar = pAr[it];
    *(uint4*)bs = pBs[it];
    if constexpr (!LAST) {
      *(uint4*)as_ = pAs[it];
      *(uint4*)br = pBr[it];
    }
#pragma unroll
    for (int j = 0; j < 8; ++j) {
      float t = bl(t8[j]) + sB1[ch + j];
      float vm = t + bl(ar[j]) + bl(bs[j]);
      hm[j] = (ok && vm > 0.f) ? fb(vm) : 0;
      if constexpr (!LAST) {
        float ve = t + bl(as_[j]) + bl(br[j]);
        he[j] = (ok && ve > 0.f) ? fb(ve) : 0;
      }
    }
    *(uint4*)(&sHm[row][ch]) = *(uint4*)hm;
    if constexpr (!LAST) *(uint4*)(&sHe[row][ch]) = *(uint4*)he;
  }
  __syncthreads();

  float bcol[8], gcol[8], becol[8];
#pragma unroll
  for (int nt = 0; nt < 8; ++nt) {
    bcol[nt] = b2[nt * 16 + l16];
    gcol[nt] = gg[nt * 16 + l16];
    becol[nt] = bb[nt * 16 + l16];
  }

  f32x4_t accM[8], accE[8];
#pragma unroll
  for (int b = 0; b < 8; ++b) {
    accM[b] = (f32x4_t){0.f, 0.f, 0.f, 0.f};
    accE[b] = (f32x4_t){0.f, 0.f, 0.f, 0.f};
  }
#pragma unroll
  for (int kk = 0; kk < 4; ++kk) {
    bf16x8_t afm = *(const bf16x8_t*)(&sHm[wave * 16 + l16][kk * 32 + q * 8]);
    bf16x8_t afe;
    if constexpr (!LAST) afe = *(const bf16x8_t*)(&sHe[wave * 16 + l16][kk * 32 + q * 8]);
#pragma unroll
    for (int nt = 0; nt < 8; ++nt) {
      bf16x8_t bfv = *(const bf16x8_t*)(wt2 + (size_t)(nt * 16 + l16) * 128 + kk * 32 + q * 8);
      accM[nt] = __builtin_amdgcn_mfma_f32_16x16x32_bf16(afm, bfv, accM[nt], 0, 0, 0);
      if constexpr (!LAST)
        accE[nt] = __builtin_amdgcn_mfma_f32_16x16x32_bf16(afe, bfv, accE[nt], 0, 0, 0);
    }
  }
  float sm[4] = {0, 0, 0, 0}, ssm[4] = {0, 0, 0, 0};
  float se[4] = {0, 0, 0, 0}, sse[4] = {0, 0, 0, 0};
#pragma unroll
  for (int r = 0; r < 4; ++r)
#pragma unroll
    for (int nt = 0; nt < 8; ++nt) {
      float vm = accM[nt][r] + bcol[nt];
      sm[r] += vm; ssm[r] += vm * vm;
      if constexpr (!LAST) {
        float ve = accE[nt][r] + bcol[nt];
        se[r] += ve; sse[r] += ve * ve;
      }
    }
#pragma unroll
  for (int r = 0; r < 4; ++r) {
#pragma unroll
    for (int m = 1; m <= 8; m <<= 1) {
      sm[r] += __shfl_xor(sm[r], m, 64);
      ssm[r] += __shfl_xor(ssm[r], m, 64);
      if constexpr (!LAST) {
        se[r] += __shfl_xor(se[r], m, 64);
        sse[r] += __shfl_xor(sse[r], m, 64);
      }
    }
  }

  if (!CSR) {
#pragma unroll
    for (int r = 0; r < 4; ++r) {
      int row = m0 + rowb + r;
      if (row >= E) continue;
      int rr = sR[rowb + r];
      float mean = sm[r] * (1.f / 128.f);
      float var = fmaxf(ssm[r] * (1.f / 128.f) - mean * mean, 0.f);
      float rstd = rsqrtf(var + 1e-5f);
#pragma unroll
      for (int nt = 0; nt < 8; ++nt) {
        float v = (accM[nt][r] + bcol[nt] - mean) * rstd * gcol[nt] + becol[nt];
        atomicAdd(&aggr[(size_t)rr * 128 + nt * 16 + l16], v);
      }
    }
  }

  __syncthreads();
#pragma unroll
  for (int r = 0; r < 4; ++r) {
    float meanM = sm[r] * (1.f / 128.f);
    float varM = fmaxf(ssm[r] * (1.f / 128.f) - meanM * meanM, 0.f);
    float rstdM = rsqrtf(varM + 1e-5f);
    if constexpr (!LAST) {
      float meanE = se[r] * (1.f / 128.f);
      float varE = fmaxf(sse[r] * (1.f / 128.f) - meanE * meanE, 0.f);
      float rstdE = rsqrtf(varE + 1e-5f);
#pragma unroll
      for (int nt = 0; nt < 8; ++nt) {
        float ve = (accE[nt][r] + bcol[nt] - meanE) * rstdE * gcol[nt] + becol[nt];
        sHe[rowb + r][nt * 16 + l16] = fb(ve);
      }
    }
    if (CSR) {
#pragma unroll
      for (int nt = 0; nt < 8; ++nt) {
        float vm = (accM[nt][r] + bcol[nt] - meanM) * rstdM * gcol[nt] + becol[nt];
        sHm[rowb + r][nt * 16 + l16] = fb(vm);
      }
    }
  }
  __syncthreads();

#pragma unroll
  for (int it = 0; it < 4; ++it) {
    int lin = it * 256 + tid;
    int row = lin >> 4, ch = (lin & 15) * 8;
    int grow = m0 + row;
    if (grow >= E) continue;
    if constexpr (!LAST) {
      u16 y8[8], e8[8];
      *(uint4*)y8 = *(uint4*)(&sHe[row][ch]);
      *(uint4*)e8 = *(const uint4*)(eh + (size_t)grow * 128 + ch);
#pragma unroll
      for (int j = 0; j < 8; ++j) y8[j] = fb(bl(y8[j]) + bl(e8[j]));
      *(uint4*)(eh + (size_t)grow * 128 + ch) = *(uint4*)y8;
    }

    if (CSR) {
      int rr = sR[row];
      if (rr < 0) continue;
      bool first = (row == 0) || (sR[row - 1] != rr);
      if (!first) continue;
      int gs = startp[rr], ge2 = startp[rr + 1];
      int le = ge2 - m0;
      if (le > 64) le = 64;
      float acc[8] = {0, 0, 0, 0, 0, 0, 0, 0};
      for (int i = row; i < le; ++i) {
        u16 m8[8];
        *(uint4*)m8 = *(uint4*)(&sHm[i][ch]);
#pragma unroll
        for (int j = 0; j < 8; ++j) acc[j] += bl(m8[j]);
      }
      if (gs >= m0 && ge2 <= m0 + 64) {
        *(float4*)(aggr + (size_t)rr * 128 + ch) = make_float4(acc[0], acc[1], acc[2], acc[3]);
        *(float4*)(aggr + (size_t)rr * 128 + ch + 4) =
            make_float4(acc[4], acc[5], acc[6], acc[7]);
      } else {
#pragma unroll
        for (int j = 0; j < 8; ++j) atomicAdd(&aggr[(size_t)rr * 128 + ch + j], acc[j]);
      }
    }
  }
}

extern "C" void kernel_launch(void* const* d_in, const int* in_sizes, int n_in, void* d_out,
                              int out_size, void* d_ws, size_t ws_size, hipStream_t stream) {
  auto F = [&](int i) { return (const float*)d_in[i]; };
  const int* edge_index = (const int*)d_in[6];
  const int N_ = in_sizes[0];
  const int E_ = in_sizes[6] / 2;

  char* wsb = (char*)d_ws;
  size_t off = 0;
  auto alloc = [&](size_t bytes) -> char* {
    char* p = wsb + off;
    off += (bytes + 255) & ~(size_t)255;
    return p;
  };
  u16* xh = (u16*)alloc((size_t)N_ * 128 * 2);
  u16* xhA = (u16*)alloc((size_t)N_ * 128 * 2);
  u16* xhB = (u16*)alloc((size_t)N_ * 128 * 2);
  u16* ehP = (u16*)alloc((size_t)E_ * 128 * 2);
  float* aggr = (float*)alloc((size_t)N_ * 128 * 4);
  u16* wne2T = (u16*)alloc(16384 * 2);
  u16* wee2T = (u16*)alloc(16384 * 2);
  u16* wpe1T = (u16*)alloc((size_t)9 * 16384 * 2);
  u16* wpe2T = (u16*)alloc((size_t)3 * 16384 * 2);
  u16* wpn1T = (u16*)alloc((size_t)6 * 16384 * 2);
  u16* wpn2T = (u16*)alloc((size_t)3 * 16384 * 2);
  u16* w1dT = (u16*)alloc(8192 * 2);

  const size_t base_off = off;
  int* startp = (int*)alloc((size_t)(N_ + 1) * 4);
  int* cntp = (int*)alloc((size_t)N_ * 4);
  int* partp = (int*)alloc((size_t)N_ * 4);
  int* bsump = (int*)alloc(((size_t)(N_ + 255) / 256) * 4 + 256);
  int* sortedS = (int*)alloc((size_t)E_ * 4);
  int* sortedR = (int*)alloc((size_t)E_ * 4);
  bool useCSR = (off <= ws_size);
  if (!useCSR) {
    off = base_off;
    if (off > ws_size) {
      sentinel_kernel<<<(out_size + 255) / 256, 256, 0, stream>>>((float*)d_out, out_size);
      return;
    }
  }

  TArgs ta;
  int ts = 0;
  ta.s[ts++] = {F(13), wne2T};
  ta.s[ts++] = {F(19), wee2T};
  for (int i = 0; i < 3; ++i)
    for (int b = 0; b < 3; ++b)
      ta.s[ts++] = {F(23) + (size_t)(i * 3 + b) * 16384, wpe1T + (size_t)(i * 3 + b) * 16384};
  for (int i = 0; i < 3; ++i) ta.s[ts++] = {F(25) + (size_t)i * 16384, wpe2T + (size_t)i * 16384};
  for (int i = 0; i < 3; ++i)
    for (int b = 0; b < 2; ++b)
      ta.s[ts++] = {F(29) + (size_t)(i * 2 + b) * 16384, wpn1T + (size_t)(i * 2 + b) * 16384};
  for (int i = 0; i < 3; ++i) ta.s[ts++] = {F(31) + (size_t)i * 16384, wpn2T + (size_t)i * 16384};

  const int tilesN = (N_ + 63) / 64;
  const int tilesE = (E_ + 63) / 64;
  const int nb = (N_ + 255) / 256;
  dim3 blk(256);

  transpose_w<<<23, blk, 0, stream>>>(ta);
  transpose_w1d<<<1, blk, 0, stream>>>(F(35), w1dT);

  const int* sArr = edge_index;
  const int* rArr = edge_index + E_;
  if (useCSR) {
    hipMemsetAsync(cntp, 0, (size_t)N_ * 4, stream);
    deg_count<<<(E_ + 255) / 256, blk, 0, stream>>>(edge_index, cntp, E_);
    scan1<<<nb, blk, 0, stream>>>(cntp, partp, bsump, N_);
    scan2<<<1, blk, 0, stream>>>(bsump, nb);
    scan3<<<nb, blk, 0, stream>>>(partp, bsump, startp, N_);
    hipMemsetAsync(cntp, 0, (size_t)N_ * 4, stream);
    fill_slot<<<(E_ + 255) / 256, blk, 0, stream>>>(edge_index, cntp, startp, sortedS, sortedR,
                                                    E_);
    sArr = sortedS;
    rArr = sortedR;
  }

  // ---- node encode (features inline; edge encode now fused into step-0 edge_fused) ----
  encode_fused<9, true, true><<<tilesN, blk, 0, stream>>>(
      F(0), F(1), F(2), F(3), F(4), F(7), F(8), nullptr, nullptr,
      F(11), F(12), wne2T, F(14), F(15), F(16), xh,
      wpe1T, wpe1T + 16384, xhA, xhB, aggr, N_);

  // ---- process steps ----
  for (int i = 0; i < 3; ++i) {
    const u16* wtC = wpe1T + (size_t)(i * 3 + 2) * 16384;
    const float* pb1 = F(24) + i * 128;
    const u16* wt2 = wpe2T + (size_t)i * 16384;
    const float* pb2 = F(26) + i * 128;
    const float* pg = F(27) + i * 128;
    const float* pbe = F(28) + i * 128;
    const u16* wtnA = wpn1T + (size_t)(i * 2 + 0) * 16384;
    const u16* wtnB = wpn1T + (size_t)(i * 2 + 1) * 16384;
    const float* nb1 = F(30) + i * 128;
    const u16* wtn2 = wpn2T + (size_t)i * 16384;
    const float* nb2 = F(32) + i * 128;
    const float* ng = F(33) + i * 128;
    const float* nbe = F(34) + i * 128;

    if (useCSR) {
      if (i == 0)
        edge_fused<true, false, true><<<tilesE, blk, 0, stream>>>(
            ehP, xhA, xhB, wtC, pb1, wt2, pb2, pg, pbe, sArr, rArr, startp, aggr,
            F(17), F(18), wee2T, F(20), F(21), F(22), F(9), F(10), F(5), F(0), E_);
      else if (i == 1)
        edge_fused<true, false, false><<<tilesE, blk, 0, stream>>>(
            ehP, xhA, xhB, wtC, pb1, wt2, pb2, pg, pbe, sArr, rArr, startp, aggr,
            nullptr, nullptr, nullptr, nullptr, nullptr, nullptr, nullptr, nullptr,
            nullptr, nullptr, E_);
      else
        edge_fused<true, true, false><<<tilesE, blk, 0, stream>>>(
            ehP, xhA, xhB, wtC, pb1, wt2, pb2, pg, pbe, sArr, rArr, startp, aggr,
            nullptr, nullptr, nullptr, nullptr, nullptr, nullptr, nullptr, nullptr,
            nullptr, nullptr, E_);
    } else {
      if (i == 0)
        edge_fused<false, false, true><<<tilesE, blk, 0, stream>>>(
            ehP, xhA, xhB, wtC, pb1, wt2, pb2, pg, pbe, sArr, rArr, nullptr, aggr,
            F(17), F(18), wee2T, F(20), F(21), F(22), F(9), F(10), F(5), F(0), E_);
      else if (i == 1)
        edge_fused<false, false, false><<<tilesE, blk, 0, stream>>>(
            ehP, xhA, xhB, wtC, pb1, wt2, pb2, pg, pbe, sArr, rArr, nullptr, aggr,
            nullptr, nullptr, nullptr, nullptr, nullptr, nullptr, nullptr, nullptr,
            nullptr, nullptr, E_);
      else
        edge_fused<false, true, false><<<tilesE, blk, 0, stream>>>(
            ehP, xhA, xhB, wtC, pb1, wt2, pb2, pg, pbe, sArr, rArr, nullptr, aggr,
            nullptr, nullptr, nullptr, nullptr, nullptr, nullptr, nullptr, nullptr,
            nullptr, nullptr, E_);
    }

    if (i == 2) {
      node_fused_2w<true><<<tilesN, blk, 0, stream>>>(
          xh, aggr, wtnA, wtnB, nb1, wtn2, nb2, ng, nbe,
          nullptr, nullptr, nullptr, nullptr,
          w1dT, F(36), F(37), F(38), (float*)d_out, N_);
    } else {
      const u16* wtA2 = wpe1T + (size_t)((i + 1) * 3 + 0) * 16384;
      const u16* wtB2 = wpe1T + (size_t)((i + 1) * 3 + 1) * 16384;
      node_fused_2w<false><<<tilesN, blk, 0, stream>>>(
          xh, aggr, wtnA, wtnB, nb1, wtn2, nb2, ng, nbe,
          wtA2, wtB2, xhA, xhB,
          nullptr, nullptr, nullptr, nullptr, nullptr, N_);
    }
  }
}

// Round 14
// 1103.497 us; speedup vs baseline: 1.0244x; 1.0244x over previous
//
#include <hip/hip_runtime.h>
#include <stdint.h>

typedef unsigned short u16;
typedef __attribute__((ext_vector_type(8))) short bf16x8_t;
typedef __attribute__((ext_vector_type(4))) float f32x4_t;

__device__ __forceinline__ float bl(u16 x) {
  union { unsigned u; float f; } c; c.u = ((unsigned)x) << 16; return c.f;
}
__device__ __forceinline__ u16 fb(float x) {
  union { float f; unsigned u; } c; c.f = x;
  unsigned r = c.u + 0x7fffu + ((c.u >> 16) & 1u);
  return (u16)(r >> 16);
}

__global__ void sentinel_kernel(float* out, int n) {
  int i = blockIdx.x * 256 + threadIdx.x;
  if (i < n) out[i] = 12345.f;
}

// ---------------- weight transpose: wT[n][k] = fb(W[k][n]) ----------------
struct TSeg { const float* src; u16* dst; };
struct TArgs { TSeg s[23]; };
__global__ void transpose_w(TArgs a) {
  __shared__ u16 sT[128][132];
  const float* src = a.s[blockIdx.x].src;
  u16* dst = a.s[blockIdx.x].dst;
  for (int e = threadIdx.x; e < 16384; e += 256) {
    int k = e >> 7, n = e & 127;
    sT[n][k] = fb(src[e]);
  }
  __syncthreads();
  for (int e = threadIdx.x; e < 16384; e += 256) {
    int n = e >> 7, k = e & 127;
    dst[e] = sT[n][k];
  }
}

// decoder W1 (128x64) -> bf16 W1^T [64][128]
__global__ void transpose_w1d(const float* __restrict__ src, u16* __restrict__ dst) {
  __shared__ u16 sT[64][132];
  for (int e = threadIdx.x; e < 8192; e += 256) {
    int k = e >> 6, n = e & 63;
    sT[n][k] = fb(src[e]);
  }
  __syncthreads();
  for (int e = threadIdx.x; e < 8192; e += 256) {
    int n = e >> 7, k = e & 127;
    dst[e] = sT[n][k];
  }
}

// ---------------- CSR build + receiver-sort ----------------
__global__ void deg_count(const int* __restrict__ ei, int* __restrict__ cnt, int E) {
  int e = blockIdx.x * 256 + threadIdx.x;
  if (e < E) atomicAdd(&cnt[ei[E + e]], 1);
}
__global__ void scan1(const int* __restrict__ cnt, int* __restrict__ part,
                      int* __restrict__ bsum, int N) {
  __shared__ int s[256];
  int i = blockIdx.x * 256 + threadIdx.x;
  s[threadIdx.x] = (i < N) ? cnt[i] : 0;
  __syncthreads();
#pragma unroll
  for (int o = 1; o < 256; o <<= 1) {
    int t = (threadIdx.x >= o) ? s[threadIdx.x - o] : 0;
    __syncthreads();
    s[threadIdx.x] += t;
    __syncthreads();
  }
  if (i < N) part[i] = s[threadIdx.x];
  if (threadIdx.x == 255) bsum[blockIdx.x] = s[255];
}
__global__ void scan2(int* bsum, int nb) {
  __shared__ int s[256];
  __shared__ int carry;
  if (threadIdx.x == 0) carry = 0;
  __syncthreads();
  for (int base = 0; base < nb; base += 256) {
    int i = base + threadIdx.x;
    int v = (i < nb) ? bsum[i] : 0;
    s[threadIdx.x] = v;
    __syncthreads();
#pragma unroll
    for (int o = 1; o < 256; o <<= 1) {
      int t = (threadIdx.x >= o) ? s[threadIdx.x - o] : 0;
      __syncthreads();
      s[threadIdx.x] += t;
      __syncthreads();
    }
    int exc = s[threadIdx.x] - v + carry;
    if (i < nb) bsum[i] = exc;
    __syncthreads();
    if (threadIdx.x == 255) carry += s[255];
    __syncthreads();
  }
}
__global__ void scan3(const int* __restrict__ part, const int* __restrict__ bsum,
                      int* __restrict__ start, int N) {
  int i = blockIdx.x * 256 + threadIdx.x;
  if (i < N) start[i + 1] = part[i] + bsum[i >> 8];
  if (i == 0) start[0] = 0;
}
__global__ void fill_slot(const int* __restrict__ ei, int* __restrict__ cnt2,
                          const int* __restrict__ start, int* __restrict__ sortedS,
                          int* __restrict__ sortedR, int E) {
  int e = blockIdx.x * 256 + threadIdx.x;
  if (e >= E) return;
  int s = ei[e], r = ei[E + e];
  int p = atomicAdd(&cnt2[r], 1);
  int slot = start[r] + p;
  sortedS[slot] = s;
  sortedR[slot] = r;
}

// ---------------- fused encoder: LN(relu(feat@W1+b1)@W2+b2) -> out ----------------
// Features computed INLINE:
//   NODE=true  (K=9): fa=t, fb=t_prev, fc=q, fd=q_prev, fe=q_next[N][5]
//   NODE=false (K=4): fa=mesh_pos[N][2], fb=t; sArr/rArr give edge endpoints
// DUAL: additionally compute out@WA, out@WB from the LN'd LDS tile and zero aggr.
template <int K, bool DUAL, bool NODE>
__global__ __launch_bounds__(256, 2) void encode_fused(
    const float* __restrict__ fa, const float* __restrict__ fb_, const float* __restrict__ fc,
    const float* __restrict__ fd, const float* __restrict__ fe,
    const float* __restrict__ fmean, const float* __restrict__ fstd,
    const int* __restrict__ sArr, const int* __restrict__ rArr,
    const float* __restrict__ w1f, const float* __restrict__ b1f,
    const u16* __restrict__ wt2, const float* __restrict__ b2, const float* __restrict__ gg,
    const float* __restrict__ bb, u16* __restrict__ out,
    const u16* __restrict__ wtA2, const u16* __restrict__ wtB2, u16* __restrict__ xhA,
    u16* __restrict__ xhB, float* __restrict__ aggr, int M) {
  __shared__ float sW1[K * 128];
  __shared__ float sB1[128];
  __shared__ float sM[16], sS[16];
  __shared__ u16 sH[64][136];
  __shared__ u16 sO1[DUAL ? 64 : 1][136];
  const int tid = threadIdx.x;
  const int wave = tid >> 6, lane = tid & 63;
  const int q = lane >> 4, l16 = lane & 15;
  const int m0 = blockIdx.x * 64;
  const int rowb = wave * 16 + q * 4;
  const int arow = m0 + wave * 16 + l16;
  const int arc = arow < M ? arow : M - 1;

  float rv[4], rq[5];
  int s_, r_;
  if constexpr (NODE) {
    rv[0] = fa[arc]; rv[1] = fb_[arc]; rv[2] = fc[arc]; rv[3] = fd[arc];
#pragma unroll
    for (int j = 0; j < 5; ++j) rq[j] = fe[(size_t)arc * 5 + j];
  } else {
    s_ = sArr[arc]; r_ = rArr[arc];
    rv[0] = fa[s_ * 2] - fa[r_ * 2];
    rv[1] = fa[s_ * 2 + 1] - fa[r_ * 2 + 1];
    rv[2] = fb_[s_];
    rv[3] = fb_[r_];
  }

  for (int i = tid; i < K * 128; i += 256) sW1[i] = w1f[i];
  if (tid < 128) sB1[tid] = b1f[tid];
  if (tid < K) { sM[tid] = fmean[tid]; sS[tid] = fstd[tid]; }
  __syncthreads();

  float fr[K];
  if constexpr (NODE) {
    float x[9];
    x[0] = rv[0]; x[1] = rv[0] - rv[1];
    x[2] = rv[2]; x[3] = rv[2] - rv[3];
#pragma unroll
    for (int j = 0; j < 5; ++j) x[4 + j] = rq[j];
#pragma unroll
    for (int k = 0; k < 9; ++k) fr[k] = (x[k] - sM[k]) / sS[k];
  } else {
    float d = sqrtf(rv[0] * rv[0] + rv[1] * rv[1]);
    float x[4] = {rv[0], rv[1], d, rv[2] - rv[3]};
#pragma unroll
    for (int k = 0; k < 4; ++k) fr[k] = (x[k] - sM[k]) / sS[k];
  }

  f32x4_t acc[8];
#pragma unroll
  for (int b = 0; b < 8; ++b) acc[b] = (f32x4_t){0.f, 0.f, 0.f, 0.f};
#pragma unroll
  for (int kk = 0; kk < 4; ++kk) {
    union { u16 u[8]; bf16x8_t v; } cv;
#pragma unroll
    for (int j = 0; j < 8; ++j) {
      int col = kk * 32 + q * 8 + j;
      float h = sB1[col];
#pragma unroll
      for (int k = 0; k < K; ++k) h += fr[k] * sW1[k * 128 + col];
      cv.u[j] = fb(h > 0.f ? h : 0.f);
    }
#pragma unroll
    for (int nt = 0; nt < 8; ++nt) {
      bf16x8_t bfv = *(const bf16x8_t*)(wt2 + (size_t)(nt * 16 + l16) * 128 + kk * 32 + q * 8);
      acc[nt] = __builtin_amdgcn_mfma_f32_16x16x32_bf16(cv.v, bfv, acc[nt], 0, 0, 0);
    }
  }

  float bcol[8], gcol[8], becol[8];
#pragma unroll
  for (int nt = 0; nt < 8; ++nt) {
    bcol[nt] = b2[nt * 16 + l16];
    gcol[nt] = gg[nt * 16 + l16];
    becol[nt] = bb[nt * 16 + l16];
  }
  float s[4] = {0, 0, 0, 0}, ss[4] = {0, 0, 0, 0};
#pragma unroll
  for (int r = 0; r < 4; ++r)
#pragma unroll
    for (int nt = 0; nt < 8; ++nt) {
      float v = acc[nt][r] + bcol[nt];
      s[r] += v;
      ss[r] += v * v;
    }
#pragma unroll
  for (int r = 0; r < 4; ++r) {
#pragma unroll
    for (int m = 1; m <= 8; m <<= 1) {
      s[r] += __shfl_xor(s[r], m, 64);
      ss[r] += __shfl_xor(ss[r], m, 64);
    }
  }
#pragma unroll
  for (int r = 0; r < 4; ++r) {
    float mean = s[r] * (1.f / 128.f);
    float var = fmaxf(ss[r] * (1.f / 128.f) - mean * mean, 0.f);
    float rstd = rsqrtf(var + 1e-5f);
#pragma unroll
    for (int nt = 0; nt < 8; ++nt) {
      float v = (acc[nt][r] + bcol[nt] - mean) * rstd * gcol[nt] + becol[nt];
      sH[rowb + r][nt * 16 + l16] = fb(v);
    }
  }
  __syncthreads();
#pragma unroll
  for (int it = 0; it < 4; ++it) {
    int lin = it * 256 + tid;
    int row = lin >> 4, ch = (lin & 15) * 8;
    int grow = m0 + row;
    if (grow >= M) continue;
    *(uint4*)(out + (size_t)grow * 128 + ch) = *(uint4*)(&sH[row][ch]);
  }

  if constexpr (DUAL) {
    {
      float4 z = make_float4(0.f, 0.f, 0.f, 0.f);
#pragma unroll
      for (int it = 0; it < 8; ++it) {
        int lin = it * 256 + tid;
        int row = lin >> 5, c4 = (lin & 31) * 4;
        int grow = m0 + row;
        if (grow < M) *(float4*)(aggr + (size_t)grow * 128 + c4) = z;
      }
    }
    f32x4_t a0[8], a1[8];
#pragma unroll
    for (int b = 0; b < 8; ++b) {
      a0[b] = (f32x4_t){0.f, 0.f, 0.f, 0.f};
      a1[b] = (f32x4_t){0.f, 0.f, 0.f, 0.f};
    }
#pragma unroll
    for (int kk = 0; kk < 4; ++kk) {
      bf16x8_t af = *(const bf16x8_t*)(&sH[wave * 16 + l16][kk * 32 + q * 8]);
#pragma unroll
      for (int nt = 0; nt < 8; ++nt) {
        bf16x8_t b0 = *(const bf16x8_t*)(wtA2 + (size_t)(nt * 16 + l16) * 128 + kk * 32 + q * 8);
        bf16x8_t b1v = *(const bf16x8_t*)(wtB2 + (size_t)(nt * 16 + l16) * 128 + kk * 32 + q * 8);
        a0[nt] = __builtin_amdgcn_mfma_f32_16x16x32_bf16(af, b0, a0[nt], 0, 0, 0);
        a1[nt] = __builtin_amdgcn_mfma_f32_16x16x32_bf16(af, b1v, a1[nt], 0, 0, 0);
      }
    }
    __syncthreads();
#pragma unroll
    for (int r = 0; r < 4; ++r)
#pragma unroll
      for (int nt = 0; nt < 8; ++nt) {
        sH[rowb + r][nt * 16 + l16] = fb(a0[nt][r]);
        sO1[rowb + r][nt * 16 + l16] = fb(a1[nt][r]);
      }
    __syncthreads();
#pragma unroll
    for (int it = 0; it < 4; ++it) {
      int lin = it * 256 + tid;
      int row = lin >> 4, ch = (lin & 15) * 8;
      int grow = m0 + row;
      if (grow >= M) continue;
      *(uint4*)(xhA + (size_t)grow * 128 + ch) = *(uint4*)(&sH[row][ch]);
      *(uint4*)(xhB + (size_t)grow * 128 + ch) = *(uint4*)(&sO1[row][ch]);
    }
  }
}

// ---------------- fused node-update (+ next-step dual GEMM / + fused decoder) --------
template <bool DEC>
__global__ __launch_bounds__(256, 2) void node_fused_2w(
    u16* __restrict__ xh, float* __restrict__ aggr, const u16* __restrict__ wtA,
    const u16* __restrict__ wtB, const float* __restrict__ b1, const u16* __restrict__ wt2,
    const float* __restrict__ b2, const float* __restrict__ gg, const float* __restrict__ bb,
    const u16* __restrict__ wtA2, const u16* __restrict__ wtB2, u16* __restrict__ xhA,
    u16* __restrict__ xhB,
    const u16* __restrict__ w1t, const float* __restrict__ db1,
    const float* __restrict__ w2d, const float* __restrict__ db2, float* __restrict__ outp,
    int M) {
  __shared__ u16 sH[64][136];
  __shared__ u16 sO1[DEC ? 1 : 64][136];
  __shared__ float sW2d[DEC ? 320 : 1];
  __shared__ float sDb1[DEC ? 64 : 1];
  const int tid = threadIdx.x;
  const int wave = tid >> 6, lane = tid & 63;
  const int q = lane >> 4, l16 = lane & 15;
  const int m0 = blockIdx.x * 64;
  const int rowb = wave * 16 + q * 4;
  const int arow = m0 + wave * 16 + l16;
  const int arc = arow < M ? arow : M - 1;

  if constexpr (DEC) {
    for (int i = tid; i < 320; i += 256) sW2d[i] = w2d[i];
    if (tid < 64) sDb1[tid] = db1[tid];
  }

  bf16x8_t xf[4], af_[4];
#pragma unroll
  for (int kk = 0; kk < 4; ++kk) {
    xf[kk] = *(const bf16x8_t*)(xh + (size_t)arc * 128 + kk * 32 + q * 8);
    const float* ap = aggr + (size_t)arc * 128 + kk * 32 + q * 8;
    union { u16 u[8]; bf16x8_t v; } cv;
#pragma unroll
    for (int j = 0; j < 8; ++j) cv.u[j] = fb(ap[j]);
    af_[kk] = cv.v;
  }

  f32x4_t acc[8];
#pragma unroll
  for (int b = 0; b < 8; ++b) acc[b] = (f32x4_t){0.f, 0.f, 0.f, 0.f};
#pragma unroll
  for (int kk = 0; kk < 4; ++kk) {
#pragma unroll
    for (int nt = 0; nt < 8; ++nt) {
      bf16x8_t bA = *(const bf16x8_t*)(wtA + (size_t)(nt * 16 + l16) * 128 + kk * 32 + q * 8);
      bf16x8_t bB = *(const bf16x8_t*)(wtB + (size_t)(nt * 16 + l16) * 128 + kk * 32 + q * 8);
      acc[nt] = __builtin_amdgcn_mfma_f32_16x16x32_bf16(af_[kk], bA, acc[nt], 0, 0, 0);
      acc[nt] = __builtin_amdgcn_mfma_f32_16x16x32_bf16(xf[kk], bB, acc[nt], 0, 0, 0);
    }
  }
  float bcol1[8];
#pragma unroll
  for (int nt = 0; nt < 8; ++nt) bcol1[nt] = b1[nt * 16 + l16];
#pragma unroll
  for (int r = 0; r < 4; ++r)
#pragma unroll
    for (int nt = 0; nt < 8; ++nt) {
      float v = acc[nt][r] + bcol1[nt];
      sH[rowb + r][nt * 16 + l16] = fb(v > 0.f ? v : 0.f);
    }
  __syncthreads();

  f32x4_t acc2[8];
#pragma unroll
  for (int b = 0; b < 8; ++b) acc2[b] = (f32x4_t){0.f, 0.f, 0.f, 0.f};
#pragma unroll
  for (int kk = 0; kk < 4; ++kk) {
    bf16x8_t afm = *(const bf16x8_t*)(&sH[wave * 16 + l16][kk * 32 + q * 8]);
#pragma unroll
    for (int nt = 0; nt < 8; ++nt) {
      bf16x8_t bfv = *(const bf16x8_t*)(wt2 + (size_t)(nt * 16 + l16) * 128 + kk * 32 + q * 8);
      acc2[nt] = __builtin_amdgcn_mfma_f32_16x16x32_bf16(afm, bfv, acc2[nt], 0, 0, 0);
    }
  }
  float bcol[8], gcol[8], becol[8];
#pragma unroll
  for (int nt = 0; nt < 8; ++nt) {
    bcol[nt] = b2[nt * 16 + l16];
    gcol[nt] = gg[nt * 16 + l16];
    becol[nt] = bb[nt * 16 + l16];
  }
  float s[4] = {0, 0, 0, 0}, ss[4] = {0, 0, 0, 0};
#pragma unroll
  for (int r = 0; r < 4; ++r)
#pragma unroll
    for (int nt = 0; nt < 8; ++nt) {
      float v = acc2[nt][r] + bcol[nt];
      s[r] += v;
      ss[r] += v * v;
    }
#pragma unroll
  for (int r = 0; r < 4; ++r) {
#pragma unroll
    for (int m = 1; m <= 8; m <<= 1) {
      s[r] += __shfl_xor(s[r], m, 64);
      ss[r] += __shfl_xor(ss[r], m, 64);
    }
  }
  __syncthreads();
#pragma unroll
  for (int r = 0; r < 4; ++r) {
    float mean = s[r] * (1.f / 128.f);
    float var = fmaxf(ss[r] * (1.f / 128.f) - mean * mean, 0.f);
    float rstd = rsqrtf(var + 1e-5f);
#pragma unroll
    for (int nt = 0; nt < 8; ++nt) {
      float v = (acc2[nt][r] + bcol[nt] - mean) * rstd * gcol[nt] + becol[nt];
      sH[rowb + r][nt * 16 + l16] = fb(v);
    }
  }
  __syncthreads();

  bf16x8_t nf[4];
#pragma unroll
  for (int kk = 0; kk < 4; ++kk) {
    u16 y8[8];
    *(uint4*)y8 = *(uint4*)(&sH[wave * 16 + l16][kk * 32 + q * 8]);
#pragma unroll
    for (int j = 0; j < 8; ++j) y8[j] = fb(bl(y8[j]) + bl((u16)xf[kk][j]));
    nf[kk] = *(bf16x8_t*)y8;
    if constexpr (!DEC) {
      if (arow < M)
        *(uint4*)(xh + (size_t)arow * 128 + kk * 32 + q * 8) = *(uint4*)y8;
    }
  }

  if constexpr (DEC) {
    __syncthreads();
    float* sHf = (float*)&sH[0][0];
    f32x4_t dacc[4];
#pragma unroll
    for (int b = 0; b < 4; ++b) dacc[b] = (f32x4_t){0.f, 0.f, 0.f, 0.f};
#pragma unroll
    for (int kk = 0; kk < 4; ++kk) {
#pragma unroll
      for (int nt = 0; nt < 4; ++nt) {
        bf16x8_t bfv = *(const bf16x8_t*)(w1t + (size_t)(nt * 16 + l16) * 128 + kk * 32 + q * 8);
        dacc[nt] = __builtin_amdgcn_mfma_f32_16x16x32_bf16(nf[kk], bfv, dacc[nt], 0, 0, 0);
      }
    }
#pragma unroll
    for (int r = 0; r < 4; ++r)
#pragma unroll
      for (int nt = 0; nt < 4; ++nt) {
        float h = dacc[nt][r] + sDb1[nt * 16 + l16];
        float hs = h * (1.f / (1.f + __expf(-h)));
        sHf[(rowb + r) * 68 + nt * 16 + l16] = hs;
      }
    __syncthreads();
    int row = tid >> 2, tq = tid & 3;
    int grow = m0 + row;
    if (grow < M) {
#pragma unroll
      for (int t0 = 0; t0 < 2; ++t0) {
        int t = (t0 == 0) ? tq : (tq == 0 ? 4 : -1);
        if (t < 0) continue;
        float p = db2[t];
        for (int k = 0; k < 64; ++k) p += sHf[row * 68 + k] * sW2d[k * 5 + t];
        outp[(size_t)grow * 5 + t] = (float)(t + 1) * p;
      }
    }
    return;
  }

  if (wtA2 == nullptr) return;

  if (arow < M) {
    float4 z = make_float4(0.f, 0.f, 0.f, 0.f);
#pragma unroll
    for (int kk = 0; kk < 4; ++kk) {
      *(float4*)(aggr + (size_t)arow * 128 + kk * 32 + q * 8) = z;
      *(float4*)(aggr + (size_t)arow * 128 + kk * 32 + q * 8 + 4) = z;
    }
  }

  f32x4_t a0[8], a1[8];
#pragma unroll
  for (int b = 0; b < 8; ++b) {
    a0[b] = (f32x4_t){0.f, 0.f, 0.f, 0.f};
    a1[b] = (f32x4_t){0.f, 0.f, 0.f, 0.f};
  }
#pragma unroll
  for (int kk = 0; kk < 4; ++kk) {
#pragma unroll
    for (int nt = 0; nt < 8; ++nt) {
      bf16x8_t b0 = *(const bf16x8_t*)(wtA2 + (size_t)(nt * 16 + l16) * 128 + kk * 32 + q * 8);
      bf16x8_t b1v = *(const bf16x8_t*)(wtB2 + (size_t)(nt * 16 + l16) * 128 + kk * 32 + q * 8);
      a0[nt] = __builtin_amdgcn_mfma_f32_16x16x32_bf16(nf[kk], b0, a0[nt], 0, 0, 0);
      a1[nt] = __builtin_amdgcn_mfma_f32_16x16x32_bf16(nf[kk], b1v, a1[nt], 0, 0, 0);
    }
  }
  __syncthreads();
#pragma unroll
  for (int r = 0; r < 4; ++r)
#pragma unroll
    for (int nt = 0; nt < 8; ++nt) {
      sH[rowb + r][nt * 16 + l16] = fb(a0[nt][r]);
      sO1[rowb + r][nt * 16 + l16] = fb(a1[nt][r]);
    }
  __syncthreads();
#pragma unroll
  for (int it = 0; it < 4; ++it) {
    int lin = it * 256 + tid;
    int row = lin >> 4, ch = (lin & 15) * 8;
    int grow = m0 + row;
    if (grow >= M) continue;
    *(uint4*)(xhA + (size_t)grow * 128 + ch) = *(uint4*)(&sH[row][ch]);
    *(uint4*)(xhB + (size_t)grow * 128 + ch) = *(uint4*)(&sO1[row][ch]);
  }
}

// ---------------- fused edge kernel (champion structure, frozen) ----------------
template <bool CSR, bool LAST>
__global__ __launch_bounds__(256, 2) void edge_fused(
    u16* __restrict__ eh, const u16* __restrict__ xhA, const u16* __restrict__ xhB,
    const u16* __restrict__ wtC, const float* __restrict__ b1, const u16* __restrict__ wt2,
    const float* __restrict__ b2, const float* __restrict__ gg, const float* __restrict__ bb,
    const int* __restrict__ sArr, const int* __restrict__ rArr,
    const int* __restrict__ startp, float* __restrict__ aggr, int E) {
  __shared__ u16 sHm[64][136];
  __shared__ u16 sHe[LAST ? 1 : 64][136];
  __shared__ int sR[64];
  __shared__ float sB1[128];
  const int tid = threadIdx.x;
  const int wave = tid >> 6, lane = tid & 63;
  const int q = lane >> 4, l16 = lane & 15;
  const int m0 = blockIdx.x * 64;
  const int rowb = wave * 16 + q * 4;
  int arow = m0 + wave * 16 + l16;
  int arc = arow < E ? arow : E - 1;

  if (tid < 64) {
    int e = m0 + tid;
    sR[tid] = (e < E) ? rArr[e] : -1;
  }
  if (tid < 128) sB1[tid] = b1[tid];

  int psv[4], prv[4];
#pragma unroll
  for (int it = 0; it < 4; ++it) {
    int lin = it * 256 + tid;
    int ge = m0 + (lin >> 4);
    int gc = ge < E ? ge : E - 1;
    psv[it] = sArr[gc];
    prv[it] = rArr[gc];
  }

  bf16x8_t ehf[4];
#pragma unroll
  for (int kk = 0; kk < 4; ++kk)
    ehf[kk] = *(const bf16x8_t*)(eh + (size_t)arc * 128 + kk * 32 + q * 8);

  f32x4_t accC[8];
#pragma unroll
  for (int b = 0; b < 8; ++b) accC[b] = (f32x4_t){0.f, 0.f, 0.f, 0.f};
#pragma unroll
  for (int kk = 0; kk < 4; ++kk) {
#pragma unroll
    for (int nt = 0; nt < 8; ++nt) {
      bf16x8_t bfv = *(const bf16x8_t*)(wtC + (size_t)(nt * 16 + l16) * 128 + kk * 32 + q * 8);
      accC[nt] = __builtin_amdgcn_mfma_f32_16x16x32_bf16(ehf[kk], bfv, accC[nt], 0, 0, 0);
    }
  }
  __builtin_amdgcn_sched_barrier(0);

  uint4 pAr[4], pBs[4], pAs[4], pBr[4];
#pragma unroll
  for (int it = 0; it < 4; ++it) {
    int ch = ((it * 256 + tid) & 15) * 8;
    pAr[it] = *(const uint4*)(xhA + (size_t)prv[it] * 128 + ch);
    pBs[it] = *(const uint4*)(xhB + (size_t)psv[it] * 128 + ch);
    if constexpr (!LAST) {
      pAs[it] = *(const uint4*)(xhA + (size_t)psv[it] * 128 + ch);
      pBr[it] = *(const uint4*)(xhB + (size_t)prv[it] * 128 + ch);
    }
  }

#pragma unroll
  for (int r = 0; r < 4; ++r)
#pragma unroll
    for (int nt = 0; nt < 8; ++nt) sHm[rowb + r][nt * 16 + l16] = fb(accC[nt][r]);
  __syncthreads();

#pragma unroll
  for (int it = 0; it < 4; ++it) {
    int lin = it * 256 + tid;
    int row = lin >> 4, ch = (lin & 15) * 8;
    bool ok = (m0 + row) < E;
    u16 t8[8], ar[8], as_[8], br[8], bs[8], hm[8], he[8];
    *(uint4*)t8 = *(uint4*)(&sHm[row][ch]);
    *(uint4*)ar = pAr[it];
    *(uint4*)bs = pBs[it];
    if constexpr (!LAST) {
      *(uint4*)as_ = pAs[it];
      *(uint4*)br = pBr[it];
    }
#pragma unroll
    for (int j = 0; j < 8; ++j) {
      float t = bl(t8[j]) + sB1[ch + j];
      float vm = t + bl(ar[j]) + bl(bs[j]);
      hm[j] = (ok && vm > 0.f) ? fb(vm) : 0;
      if constexpr (!LAST) {
        float ve = t + bl(as_[j]) + bl(br[j]);
        he[j] = (ok && ve > 0.f) ? fb(ve) : 0;
      }
    }
    *(uint4*)(&sHm[row][ch]) = *(uint4*)hm;
    if constexpr (!LAST) *(uint4*)(&sHe[row][ch]) = *(uint4*)he;
  }
  __syncthreads();

  float bcol[8], gcol[8], becol[8];
#pragma unroll
  for (int nt = 0; nt < 8; ++nt) {
    bcol[nt] = b2[nt * 16 + l16];
    gcol[nt] = gg[nt * 16 + l16];
    becol[nt] = bb[nt * 16 + l16];
  }

  f32x4_t accM[8], accE[8];
#pragma unroll
  for (int b = 0; b < 8; ++b) {
    accM[b] = (f32x4_t){0.f, 0.f, 0.f, 0.f};
    accE[b] = (f32x4_t){0.f, 0.f, 0.f, 0.f};
  }
#pragma unroll
  for (int kk = 0; kk < 4; ++kk) {
    bf16x8_t afm = *(const bf16x8_t*)(&sHm[wave * 16 + l16][kk * 32 + q * 8]);
    bf16x8_t afe;
    if constexpr (!LAST) afe = *(const bf16x8_t*)(&sHe[wave * 16 + l16][kk * 32 + q * 8]);
#pragma unroll
    for (int nt = 0; nt < 8; ++nt) {
      bf16x8_t bfv = *(const bf16x8_t*)(wt2 + (size_t)(nt * 16 + l16) * 128 + kk * 32 + q * 8);
      accM[nt] = __builtin_amdgcn_mfma_f32_16x16x32_bf16(afm, bfv, accM[nt], 0, 0, 0);
      if constexpr (!LAST)
        accE[nt] = __builtin_amdgcn_mfma_f32_16x16x32_bf16(afe, bfv, accE[nt], 0, 0, 0);
    }
  }
  float sm[4] = {0, 0, 0, 0}, ssm[4] = {0, 0, 0, 0};
  float se[4] = {0, 0, 0, 0}, sse[4] = {0, 0, 0, 0};
#pragma unroll
  for (int r = 0; r < 4; ++r)
#pragma unroll
    for (int nt = 0; nt < 8; ++nt) {
      float vm = accM[nt][r] + bcol[nt];
      sm[r] += vm; ssm[r] += vm * vm;
      if constexpr (!LAST) {
        float ve = accE[nt][r] + bcol[nt];
        se[r] += ve; sse[r] += ve * ve;
      }
    }
#pragma unroll
  for (int r = 0; r < 4; ++r) {
#pragma unroll
    for (int m = 1; m <= 8; m <<= 1) {
      sm[r] += __shfl_xor(sm[r], m, 64);
      ssm[r] += __shfl_xor(ssm[r], m, 64);
      if constexpr (!LAST) {
        se[r] += __shfl_xor(se[r], m, 64);
        sse[r] += __shfl_xor(sse[r], m, 64);
      }
    }
  }

  if (!CSR) {
#pragma unroll
    for (int r = 0; r < 4; ++r) {
      int row = m0 + rowb + r;
      if (row >= E) continue;
      int rr = sR[rowb + r];
      float mean = sm[r] * (1.f / 128.f);
      float var = fmaxf(ssm[r] * (1.f / 128.f) - mean * mean, 0.f);
      float rstd = rsqrtf(var + 1e-5f);
#pragma unroll
      for (int nt = 0; nt < 8; ++nt) {
        float v = (accM[nt][r] + bcol[nt] - mean) * rstd * gcol[nt] + becol[nt];
        atomicAdd(&aggr[(size_t)rr * 128 + nt * 16 + l16], v);
      }
    }
  }

  __syncthreads();
#pragma unroll
  for (int r = 0; r < 4; ++r) {
    float meanM = sm[r] * (1.f / 128.f);
    float varM = fmaxf(ssm[r] * (1.f / 128.f) - meanM * meanM, 0.f);
    float rstdM = rsqrtf(varM + 1e-5f);
    if constexpr (!LAST) {
      float meanE = se[r] * (1.f / 128.f);
      float varE = fmaxf(sse[r] * (1.f / 128.f) - meanE * meanE, 0.f);
      float rstdE = rsqrtf(varE + 1e-5f);
#pragma unroll
      for (int nt = 0; nt < 8; ++nt) {
        float ve = (accE[nt][r] + bcol[nt] - meanE) * rstdE * gcol[nt] + becol[nt];
        sHe[rowb + r][nt * 16 + l16] = fb(ve);
      }
    }
    if (CSR) {
#pragma unroll
      for (int nt = 0; nt < 8; ++nt) {
        float vm = (accM[nt][r] + bcol[nt] - meanM) * rstdM * gcol[nt] + becol[nt];
        sHm[rowb + r][nt * 16 + l16] = fb(vm);
      }
    }
  }
  __syncthreads();

#pragma unroll
  for (int it = 0; it < 4; ++it) {
    int lin = it * 256 + tid;
    int row = lin >> 4, ch = (lin & 15) * 8;
    int grow = m0 + row;
    if (grow >= E) continue;
    if constexpr (!LAST) {
      u16 y8[8], e8[8];
      *(uint4*)y8 = *(uint4*)(&sHe[row][ch]);
      *(uint4*)e8 = *(const uint4*)(eh + (size_t)grow * 128 + ch);
#pragma unroll
      for (int j = 0; j < 8; ++j) y8[j] = fb(bl(y8[j]) + bl(e8[j]));
      *(uint4*)(eh + (size_t)grow * 128 + ch) = *(uint4*)y8;
    }

    if (CSR) {
      int rr = sR[row];
      if (rr < 0) continue;
      bool first = (row == 0) || (sR[row - 1] != rr);
      if (!first) continue;
      int gs = startp[rr], ge2 = startp[rr + 1];
      int le = ge2 - m0;
      if (le > 64) le = 64;
      float acc[8] = {0, 0, 0, 0, 0, 0, 0, 0};
      for (int i = row; i < le; ++i) {
        u16 m8[8];
        *(uint4*)m8 = *(uint4*)(&sHm[i][ch]);
#pragma unroll
        for (int j = 0; j < 8; ++j) acc[j] += bl(m8[j]);
      }
      if (gs >= m0 && ge2 <= m0 + 64) {
        *(float4*)(aggr + (size_t)rr * 128 + ch) = make_float4(acc[0], acc[1], acc[2], acc[3]);
        *(float4*)(aggr + (size_t)rr * 128 + ch + 4) =
            make_float4(acc[4], acc[5], acc[6], acc[7]);
      } else {
#pragma unroll
        for (int j = 0; j < 8; ++j) atomicAdd(&aggr[(size_t)rr * 128 + ch + j], acc[j]);
      }
    }
  }
}

extern "C" void kernel_launch(void* const* d_in, const int* in_sizes, int n_in, void* d_out,
                              int out_size, void* d_ws, size_t ws_size, hipStream_t stream) {
  auto F = [&](int i) { return (const float*)d_in[i]; };
  const int* edge_index = (const int*)d_in[6];
  const int N_ = in_sizes[0];
  const int E_ = in_sizes[6] / 2;

  char* wsb = (char*)d_ws;
  size_t off = 0;
  auto alloc = [&](size_t bytes) -> char* {
    char* p = wsb + off;
    off += (bytes + 255) & ~(size_t)255;
    return p;
  };
  u16* xh = (u16*)alloc((size_t)N_ * 128 * 2);
  u16* xhA = (u16*)alloc((size_t)N_ * 128 * 2);
  u16* xhB = (u16*)alloc((size_t)N_ * 128 * 2);
  u16* ehP = (u16*)alloc((size_t)E_ * 128 * 2);
  float* aggr = (float*)alloc((size_t)N_ * 128 * 4);
  u16* wne2T = (u16*)alloc(16384 * 2);
  u16* wee2T = (u16*)alloc(16384 * 2);
  u16* wpe1T = (u16*)alloc((size_t)9 * 16384 * 2);
  u16* wpe2T = (u16*)alloc((size_t)3 * 16384 * 2);
  u16* wpn1T = (u16*)alloc((size_t)6 * 16384 * 2);
  u16* wpn2T = (u16*)alloc((size_t)3 * 16384 * 2);
  u16* w1dT = (u16*)alloc(8192 * 2);

  const size_t base_off = off;
  int* startp = (int*)alloc((size_t)(N_ + 1) * 4);
  int* cntp = (int*)alloc((size_t)N_ * 4);
  int* partp = (int*)alloc((size_t)N_ * 4);
  int* bsump = (int*)alloc(((size_t)(N_ + 255) / 256) * 4 + 256);
  int* sortedS = (int*)alloc((size_t)E_ * 4);
  int* sortedR = (int*)alloc((size_t)E_ * 4);
  bool useCSR = (off <= ws_size);
  if (!useCSR) {
    off = base_off;
    if (off > ws_size) {
      sentinel_kernel<<<(out_size + 255) / 256, 256, 0, stream>>>((float*)d_out, out_size);
      return;
    }
  }

  TArgs ta;
  int ts = 0;
  ta.s[ts++] = {F(13), wne2T};
  ta.s[ts++] = {F(19), wee2T};
  for (int i = 0; i < 3; ++i)
    for (int b = 0; b < 3; ++b)
      ta.s[ts++] = {F(23) + (size_t)(i * 3 + b) * 16384, wpe1T + (size_t)(i * 3 + b) * 16384};
  for (int i = 0; i < 3; ++i) ta.s[ts++] = {F(25) + (size_t)i * 16384, wpe2T + (size_t)i * 16384};
  for (int i = 0; i < 3; ++i)
    for (int b = 0; b < 2; ++b)
      ta.s[ts++] = {F(29) + (size_t)(i * 2 + b) * 16384, wpn1T + (size_t)(i * 2 + b) * 16384};
  for (int i = 0; i < 3; ++i) ta.s[ts++] = {F(31) + (size_t)i * 16384, wpn2T + (size_t)i * 16384};

  const int tilesN = (N_ + 63) / 64;
  const int tilesE = (E_ + 63) / 64;
  const int nb = (N_ + 255) / 256;
  dim3 blk(256);

  transpose_w<<<23, blk, 0, stream>>>(ta);
  transpose_w1d<<<1, blk, 0, stream>>>(F(35), w1dT);

  const int* sArr = edge_index;
  const int* rArr = edge_index + E_;
  if (useCSR) {
    hipMemsetAsync(cntp, 0, (size_t)N_ * 4, stream);
    deg_count<<<(E_ + 255) / 256, blk, 0, stream>>>(edge_index, cntp, E_);
    scan1<<<nb, blk, 0, stream>>>(cntp, partp, bsump, N_);
    scan2<<<1, blk, 0, stream>>>(bsump, nb);
    scan3<<<nb, blk, 0, stream>>>(partp, bsump, startp, N_);
    hipMemsetAsync(cntp, 0, (size_t)N_ * 4, stream);
    fill_slot<<<(E_ + 255) / 256, blk, 0, stream>>>(edge_index, cntp, startp, sortedS, sortedR,
                                                    E_);
    sArr = sortedS;
    rArr = sortedR;
  }

  // ---- encode (features computed inline) ----
  encode_fused<4, false, false><<<tilesE, blk, 0, stream>>>(
      F(5), F(0), nullptr, nullptr, nullptr, F(9), F(10), sArr, rArr,
      F(17), F(18), wee2T, F(20), F(21), F(22), ehP,
      nullptr, nullptr, nullptr, nullptr, nullptr, E_);
  encode_fused<9, true, true><<<tilesN, blk, 0, stream>>>(
      F(0), F(1), F(2), F(3), F(4), F(7), F(8), nullptr, nullptr,
      F(11), F(12), wne2T, F(14), F(15), F(16), xh,
      wpe1T, wpe1T + 16384, xhA, xhB, aggr, N_);

  // ---- process steps ----
  for (int i = 0; i < 3; ++i) {
    const u16* wtC = wpe1T + (size_t)(i * 3 + 2) * 16384;
    const float* pb1 = F(24) + i * 128;
    const u16* wt2 = wpe2T + (size_t)i * 16384;
    const float* pb2 = F(26) + i * 128;
    const float* pg = F(27) + i * 128;
    const float* pbe = F(28) + i * 128;
    const u16* wtnA = wpn1T + (size_t)(i * 2 + 0) * 16384;
    const u16* wtnB = wpn1T + (size_t)(i * 2 + 1) * 16384;
    const float* nb1 = F(30) + i * 128;
    const u16* wtn2 = wpn2T + (size_t)i * 16384;
    const float* nb2 = F(32) + i * 128;
    const float* ng = F(33) + i * 128;
    const float* nbe = F(34) + i * 128;

    const bool last = (i == 2);
    if (useCSR) {
      if (last)
        edge_fused<true, true><<<tilesE, blk, 0, stream>>>(ehP, xhA, xhB, wtC, pb1, wt2, pb2,
                                                           pg, pbe, sArr, rArr, startp, aggr, E_);
      else
        edge_fused<true, false><<<tilesE, blk, 0, stream>>>(ehP, xhA, xhB, wtC, pb1, wt2, pb2,
                                                            pg, pbe, sArr, rArr, startp, aggr, E_);
    } else {
      if (last)
        edge_fused<false, true><<<tilesE, blk, 0, stream>>>(ehP, xhA, xhB, wtC, pb1, wt2, pb2,
                                                            pg, pbe, sArr, rArr, nullptr, aggr, E_);
      else
        edge_fused<false, false><<<tilesE, blk, 0, stream>>>(ehP, xhA, xhB, wtC, pb1, wt2, pb2,
                                                             pg, pbe, sArr, rArr, nullptr, aggr, E_);
    }
    if (last) {
      node_fused_2w<true><<<tilesN, blk, 0, stream>>>(
          xh, aggr, wtnA, wtnB, nb1, wtn2, nb2, ng, nbe,
          nullptr, nullptr, nullptr, nullptr,
          w1dT, F(36), F(37), F(38), (float*)d_out, N_);
    } else {
      const u16* wtA2 = wpe1T + (size_t)((i + 1) * 3 + 0) * 16384;
      const u16* wtB2 = wpe1T + (size_t)((i + 1) * 3 + 1) * 16384;
      node_fused_2w<false><<<tilesN, blk, 0, stream>>>(
          xh, aggr, wtnA, wtnB, nb1, wtn2, nb2, ng, nbe,
          wtA2, wtB2, xhA, xhB,
          nullptr, nullptr, nullptr, nullptr, nullptr, N_);
    }
  }
}